// Round 9
// baseline (23.224 us; speedup 1.0000x reference)
//
#include <hip/hip_runtime.h>
#include <math.h>

#define CANON_EPS 1e-4f

// 4-byte-aligned float quad: legal at any dword-aligned address; the compiler
// may merge the member loads into global_load_dwordx4 (HW only needs dword
// alignment), and even unmerged the 12 dword loads issue back-to-back.
struct f4u { float a, b, c, d; };

// ---------------------------------------------------------------------------
// Kernel 1: CSR boundaries from sorted batch. int4-vectorized: 4 atoms/thread.
// Every entry of wsi[0..G] written exactly once (empty graphs included).
// ---------------------------------------------------------------------------
__global__ __launch_bounds__(256) void build_starts_kernel(
    const int* __restrict__ batch, int* __restrict__ wsi, int n, int G) {
  int t = (int)(blockIdx.x * (unsigned)blockDim.x + threadIdx.x);
  int base = t * 4;
  if (base >= n) return;

  int b0, b1, b2, b3;
  if (base + 4 <= n) {
    int4 b4 = *reinterpret_cast<const int4*>(batch + base);
    b0 = b4.x; b1 = b4.y; b2 = b4.z; b3 = b4.w;
  } else {  // tail (n % 4 != 0)
    b0 = batch[base];
    b1 = (base + 1 < n) ? batch[base + 1] : b0;
    b2 = (base + 2 < n) ? batch[base + 2] : b1;
    b3 = (base + 3 < n) ? batch[base + 3] : b2;
  }
  int bp = (base > 0) ? batch[base - 1] : -1;

  int B[4] = {b0, b1, b2, b3};
#pragma unroll
  for (int j = 0; j < 4; ++j) {
    int i = base + j;
    if (i >= n) break;
    int prev = (j == 0) ? bp : B[j - 1];
    int b = B[j];
    for (int g = prev + 1; g <= b; ++g) wsi[g] = i;
    if (i == n - 1) {
      for (int g = b + 1; g <= G; ++g) wsi[g] = n;
    }
  }
}

// ---------------------------------------------------------------------------
// Branch-free 3x3 symmetric Jacobi eigensolver in f32, 4 cyclic sweeps.
// Columns of Q = eigenvectors; eigenvalues sorted ascending (matches eigh).
// ---------------------------------------------------------------------------
__device__ __forceinline__ void jacobi3_f32(float a00, float a11, float a22,
                                            float a01, float a02, float a12,
                                            float Q[3][3]) {
  float A00 = a00, A11 = a11, A22 = a22;
  float A01 = a01, A02 = a02, A12 = a12;
  float Q00 = 1.f, Q01 = 0.f, Q02 = 0.f;
  float Q10 = 0.f, Q11 = 1.f, Q12 = 0.f;
  float Q20 = 0.f, Q21 = 0.f, Q22 = 1.f;

#define ROT(App, Aqq, Apq, Akp, Akq, Qrp0, Qrq0, Qrp1, Qrq1, Qrp2, Qrq2)     \
  {                                                                          \
    float apq = Apq;                                                         \
    float theta = (Aqq - App) / (2.0f * apq);                                \
    float t = copysignf(1.0f, theta) /                                       \
              (fabsf(theta) + sqrtf(1.0f + theta * theta));                  \
    t = (apq == 0.0f) ? 0.0f : t; /* kills 0/0 NaN path */                   \
    float c = 1.0f / sqrtf(1.0f + t * t);                                    \
    float s = t * c;                                                         \
    App = App - t * apq;                                                     \
    Aqq = Aqq + t * apq;                                                     \
    Apq = 0.0f;                                                              \
    float akp = Akp, akq = Akq;                                              \
    Akp = c * akp - s * akq;                                                 \
    Akq = s * akp + c * akq;                                                 \
    float r0p = Qrp0, r0q = Qrq0;                                            \
    Qrp0 = c * r0p - s * r0q;                                                \
    Qrq0 = s * r0p + c * r0q;                                                \
    float r1p = Qrp1, r1q = Qrq1;                                            \
    Qrp1 = c * r1p - s * r1q;                                                \
    Qrq1 = s * r1p + c * r1q;                                                \
    float r2p = Qrp2, r2q = Qrq2;                                            \
    Qrp2 = c * r2p - s * r2q;                                                \
    Qrq2 = s * r2p + c * r2q;                                                \
  }

#pragma unroll
  for (int sweep = 0; sweep < 4; ++sweep) {
    ROT(A00, A11, A01, A02, A12, Q00, Q01, Q10, Q11, Q20, Q21);
    ROT(A00, A22, A02, A01, A12, Q00, Q02, Q10, Q12, Q20, Q22);
    ROT(A11, A22, A12, A01, A02, Q01, Q02, Q11, Q12, Q21, Q22);
  }
#undef ROT

  float w0 = A00, w1 = A11, w2 = A22;
#define CSWAP(wa, wb, qa0, qb0, qa1, qb1, qa2, qb2)                          \
  {                                                                          \
    bool sw = (wb) < (wa);                                                   \
    float tw = wa; wa = sw ? wb : wa; wb = sw ? tw : wb;                     \
    float t0 = qa0; qa0 = sw ? qb0 : qa0; qb0 = sw ? t0 : qb0;               \
    float t1 = qa1; qa1 = sw ? qb1 : qa1; qb1 = sw ? t1 : qb1;               \
    float t2 = qa2; qa2 = sw ? qb2 : qa2; qb2 = sw ? t2 : qb2;               \
  }
  CSWAP(w0, w1, Q00, Q01, Q10, Q11, Q20, Q21);
  CSWAP(w1, w2, Q01, Q02, Q11, Q12, Q21, Q22);
  CSWAP(w0, w1, Q00, Q01, Q10, Q11, Q20, Q21);
#undef CSWAP

  Q[0][0] = Q00; Q[0][1] = Q01; Q[0][2] = Q02;
  Q[1][0] = Q10; Q[1][1] = Q11; Q[1][2] = Q12;
  Q[2][0] = Q20; Q[2][1] = Q21; Q[2][2] = Q22;
}

// ---------------------------------------------------------------------------
// Kernel 2 (fused): moments + eigen + sign + output. 16 lanes/graph,
// 16 graphs per 256-thread block.
// Phase A: lane `sub` stages atoms s+4*sub..+3 (round 0) and +64 (round 1) as
//   3 quad loads each — phase-aligned x/y/z, one waitcnt round, covers 128
//   atoms (scalar epilogue for more). Butterfly-reduce 9 moments.
//   Lane sub==0 stashes {moments, its 4 raw staged atoms, s, cnt} in LDS.
// Phase B: threads 0..15 each run Jacobi + sign (from the cached first-4
//   atoms; global fallback is ~never taken) + output write for one graph.
// ---------------------------------------------------------------------------
__global__ __launch_bounds__(256) void fused_kernel(
    const float* __restrict__ pos, const int* __restrict__ wsi,
    float* __restrict__ out, int n, int G) {
  __shared__ float lmom[16][9];   // cx,cy,cz,ixx,iyy,izz,ixy,ixz,iyz
  __shared__ float latm[16][12];  // first 4 atoms, raw
  __shared__ int lsc[16][2];      // s, cnt

  int tid = (int)threadIdx.x;
  int lg = tid >> 4;   // local graph
  int sub = tid & 15;  // lane within subgroup
  int gid = (int)blockIdx.x * 16 + lg;

  int s = 0, e = 0;
  if (gid < G) {
    s = wsi[gid];
    e = wsi[gid + 1];
  }
  int cnt = e - s;

  // ---- stage two rounds of 4 consecutive atoms (12 floats) per lane ------
  int a0 = s + sub * 4;
  int a1 = a0 + 64;
  int c0 = min(a0, n - 4); c0 = c0 < 0 ? 0 : c0;
  int c1 = min(a1, n - 4); c1 = c1 < 0 ? 0 : c1;
  const f4u* p0 = reinterpret_cast<const f4u*>(pos + (size_t)3 * c0);
  const f4u* p1 = reinterpret_cast<const f4u*>(pos + (size_t)3 * c1);
  f4u v0 = p0[0], v1 = p0[1], v2 = p0[2];
  f4u u0 = p1[0], u1 = p1[1], u2 = p1[2];

  float sx = 0.f, sy = 0.f, sz = 0.f;
  float sxx = 0.f, syy = 0.f, szz = 0.f, sxy = 0.f, sxz = 0.f, syz = 0.f;
  int rem = cnt - sub * 4;  // round-0 valid atoms: j < rem; round-1: j+64 < rem

#define ACC3(X, Y, Z, V)                                                     \
  {                                                                          \
    float m = (V) ? 1.0f : 0.0f;                                             \
    float x = (X) * m, y = (Y) * m, z = (Z) * m;                             \
    sx += x; sy += y; sz += z;                                               \
    sxx = fmaf(x, x, sxx); syy = fmaf(y, y, syy); szz = fmaf(z, z, szz);     \
    sxy = fmaf(x, y, sxy); sxz = fmaf(x, z, sxz); syz = fmaf(y, z, syz);     \
  }
  ACC3(v0.a, v0.b, v0.c, 0 < rem)
  ACC3(v0.d, v1.a, v1.b, 1 < rem)
  ACC3(v1.c, v1.d, v2.a, 2 < rem)
  ACC3(v2.b, v2.c, v2.d, 3 < rem)
  ACC3(u0.a, u0.b, u0.c, 64 < rem)
  ACC3(u0.d, u1.a, u1.b, 65 < rem)
  ACC3(u1.c, u1.d, u2.a, 66 < rem)
  ACC3(u2.b, u2.c, u2.d, 67 < rem)
  // rare epilogue: graphs with more than 128 atoms
  for (int i = s + 128 + sub; i < e; i += 16) {
    float x = pos[3 * i + 0], y = pos[3 * i + 1], z = pos[3 * i + 2];
    sx += x; sy += y; sz += z;
    sxx = fmaf(x, x, sxx); syy = fmaf(y, y, syy); szz = fmaf(z, z, szz);
    sxy = fmaf(x, y, sxy); sxz = fmaf(x, z, sxz); syz = fmaf(y, z, syz);
  }
#undef ACC3

#define RED16(v)                                                             \
  v += __shfl_xor(v, 1); v += __shfl_xor(v, 2);                              \
  v += __shfl_xor(v, 4); v += __shfl_xor(v, 8);
  RED16(sx) RED16(sy) RED16(sz)
  RED16(sxx) RED16(syy) RED16(szz)
  RED16(sxy) RED16(sxz) RED16(syz)
#undef RED16

  if (sub == 0 && gid < G) {
    float fn = (float)(cnt > 0 ? cnt : 1);
    float inv = 1.0f / fn;
    float mx = sx * inv, my = sy * inv, mz = sz * inv;
    float Sxx = fmaf(-fn * mx, mx, sxx);
    float Syy = fmaf(-fn * my, my, syy);
    float Szz = fmaf(-fn * mz, mz, szz);
    float Sxy = fmaf(-fn * mx, my, sxy);
    float Sxz = fmaf(-fn * mx, mz, sxz);
    float Syz = fmaf(-fn * my, mz, syz);
    lmom[lg][0] = mx; lmom[lg][1] = my; lmom[lg][2] = mz;
    lmom[lg][3] = Syy + Szz;   // ixx
    lmom[lg][4] = Sxx + Szz;   // iyy
    lmom[lg][5] = Sxx + Syy;   // izz
    lmom[lg][6] = -Sxy;        // ixy
    lmom[lg][7] = -Sxz;        // ixz
    lmom[lg][8] = -Syz;        // iyz
    // raw first-4 atoms (this lane staged exactly atoms s..s+3 in round 0)
    latm[lg][0] = v0.a; latm[lg][1] = v0.b; latm[lg][2]  = v0.c;
    latm[lg][3] = v0.d; latm[lg][4] = v1.a; latm[lg][5]  = v1.b;
    latm[lg][6] = v1.c; latm[lg][7] = v1.d; latm[lg][8]  = v2.a;
    latm[lg][9] = v2.b; latm[lg][10] = v2.c; latm[lg][11] = v2.d;
    lsc[lg][0] = s; lsc[lg][1] = cnt;
  }
  __syncthreads();

  // ---- phase B: one thread per graph -------------------------------------
  if (tid < 16) {
    int g = (int)blockIdx.x * 16 + tid;
    if (g < G) {
      float cx = lmom[tid][0], cy = lmom[tid][1], cz = lmom[tid][2];
      float Q[3][3];
      jacobi3_f32(lmom[tid][3], lmom[tid][4], lmom[tid][5], lmom[tid][6],
                  lmom[tid][7], lmom[tid][8], Q);

      float q00 = Q[0][0], q10 = Q[1][0], q20 = Q[2][0];
      float q01 = Q[0][1], q11 = Q[1][1], q21 = Q[2][1];

      int s2 = lsc[tid][0];
      int cnt2 = lsc[tid][1];

      bool found0 = false, found1 = false;
      float v0s = 0.f, v1s = 0.f;
#define CHECK(J)                                                             \
  if ((J) < cnt2) {                                                          \
    float x = latm[tid][3 * (J) + 0] - cx;                                   \
    float y = latm[tid][3 * (J) + 1] - cy;                                   \
    float z = latm[tid][3 * (J) + 2] - cz;                                   \
    float p0 = x * q00 + y * q10 + z * q20;                                  \
    float p1 = x * q01 + y * q11 + z * q21;                                  \
    if (!found0 && fabsf(p0) > CANON_EPS) { v0s = p0; found0 = true; }       \
    if (!found1 && fabsf(p1) > CANON_EPS) { v1s = p1; found1 = true; }       \
  }
      CHECK(0) CHECK(1) CHECK(2) CHECK(3)
#undef CHECK
      // ~never taken: sign not decided within the first 4 atoms
      for (int i = s2 + 4; i < s2 + cnt2 && !(found0 && found1); ++i) {
        float x = pos[3 * i + 0] - cx;
        float y = pos[3 * i + 1] - cy;
        float z = pos[3 * i + 2] - cz;
        float p0 = x * q00 + y * q10 + z * q20;
        float p1 = x * q01 + y * q11 + z * q21;
        if (!found0 && fabsf(p0) > CANON_EPS) { v0s = p0; found0 = true; }
        if (!found1 && fabsf(p1) > CANON_EPS) { v1s = p1; found1 = true; }
      }
      float s0 = (found0 && v0s < 0.f) ? -1.f : 1.f;
      float s1 = (found1 && v1s < 0.f) ? -1.f : 1.f;

      float q0x = q00 * s0, q0y = q10 * s0, q0z = q20 * s0;
      float q1x = q01 * s1, q1y = q11 * s1, q1z = q21 * s1;
      float q2x = q0y * q1z - q0z * q1y;
      float q2y = q0z * q1x - q0x * q1z;
      float q2z = q0x * q1y - q0y * q1x;
      float* o = out + (size_t)g * 9;
      o[0] = q0x; o[1] = q1x; o[2] = q2x;
      o[3] = q0y; o[4] = q1y; o[5] = q2y;
      o[6] = q0z; o[7] = q1z; o[8] = q2z;
    }
  }
}

extern "C" void kernel_launch(void* const* d_in, const int* in_sizes, int n_in,
                              void* d_out, int out_size, void* d_ws, size_t ws_size,
                              hipStream_t stream) {
  const float* pos = (const float*)d_in[0];
  const int* batch = (const int*)d_in[1];
  float* out = (float*)d_out;

  int n = in_sizes[0] / 3;  // N atoms
  int G = out_size / 9;     // graphs

  int* wsi = (int*)d_ws;  // (G+1) ints: graph start offsets

  int t1 = (n + 3) / 4;
  build_starts_kernel<<<(t1 + 255) / 256, 256, 0, stream>>>(batch, wsi, n, G);

  // 16 graphs per 256-thread block
  fused_kernel<<<(G + 15) / 16, 256, 0, stream>>>(pos, wsi, out, n, G);
}

// Round 10
// 22.057 us; speedup vs baseline: 1.0529x; 1.0529x over previous
//
#include <hip/hip_runtime.h>
#include <math.h>

#define CANON_EPS 1e-4f

// ---------------------------------------------------------------------------
// Kernel 1: CSR boundaries from sorted batch. int4-vectorized: 4 atoms/thread.
// Every entry of wsi[0..G] written exactly once (empty graphs included).
// ---------------------------------------------------------------------------
__global__ __launch_bounds__(256) void build_starts_kernel(
    const int* __restrict__ batch, int* __restrict__ wsi, int n, int G) {
  int t = (int)(blockIdx.x * (unsigned)blockDim.x + threadIdx.x);
  int base = t * 4;
  if (base >= n) return;

  int b0, b1, b2, b3;
  if (base + 4 <= n) {
    int4 b4 = *reinterpret_cast<const int4*>(batch + base);
    b0 = b4.x; b1 = b4.y; b2 = b4.z; b3 = b4.w;
  } else {  // tail (n % 4 != 0)
    b0 = batch[base];
    b1 = (base + 1 < n) ? batch[base + 1] : b0;
    b2 = (base + 2 < n) ? batch[base + 2] : b1;
    b3 = (base + 3 < n) ? batch[base + 3] : b2;
  }
  int bp = (base > 0) ? batch[base - 1] : -1;

  int B[4] = {b0, b1, b2, b3};
#pragma unroll
  for (int j = 0; j < 4; ++j) {
    int i = base + j;
    if (i >= n) break;
    int prev = (j == 0) ? bp : B[j - 1];
    int b = B[j];
    for (int g = prev + 1; g <= b; ++g) wsi[g] = i;
    if (i == n - 1) {
      for (int g = b + 1; g <= G; ++g) wsi[g] = n;
    }
  }
}

// ---------------------------------------------------------------------------
// Branch-free 3x3 symmetric Jacobi eigensolver in f32, 4 cyclic sweeps.
// Columns of Q = eigenvectors; eigenvalues sorted ascending (matches eigh).
// ---------------------------------------------------------------------------
__device__ __forceinline__ void jacobi3_f32(float a00, float a11, float a22,
                                            float a01, float a02, float a12,
                                            float Q[3][3]) {
  float A00 = a00, A11 = a11, A22 = a22;
  float A01 = a01, A02 = a02, A12 = a12;
  float Q00 = 1.f, Q01 = 0.f, Q02 = 0.f;
  float Q10 = 0.f, Q11 = 1.f, Q12 = 0.f;
  float Q20 = 0.f, Q21 = 0.f, Q22 = 1.f;

#define ROT(App, Aqq, Apq, Akp, Akq, Qrp0, Qrq0, Qrp1, Qrq1, Qrp2, Qrq2)     \
  {                                                                          \
    float apq = Apq;                                                         \
    float theta = (Aqq - App) / (2.0f * apq);                                \
    float t = copysignf(1.0f, theta) /                                       \
              (fabsf(theta) + sqrtf(1.0f + theta * theta));                  \
    t = (apq == 0.0f) ? 0.0f : t; /* kills 0/0 NaN path */                   \
    float c = 1.0f / sqrtf(1.0f + t * t);                                    \
    float s = t * c;                                                         \
    App = App - t * apq;                                                     \
    Aqq = Aqq + t * apq;                                                     \
    Apq = 0.0f;                                                              \
    float akp = Akp, akq = Akq;                                              \
    Akp = c * akp - s * akq;                                                 \
    Akq = s * akp + c * akq;                                                 \
    float r0p = Qrp0, r0q = Qrq0;                                            \
    Qrp0 = c * r0p - s * r0q;                                                \
    Qrq0 = s * r0p + c * r0q;                                                \
    float r1p = Qrp1, r1q = Qrq1;                                            \
    Qrp1 = c * r1p - s * r1q;                                                \
    Qrq1 = s * r1p + c * r1q;                                                \
    float r2p = Qrp2, r2q = Qrq2;                                            \
    Qrp2 = c * r2p - s * r2q;                                                \
    Qrq2 = s * r2p + c * r2q;                                                \
  }

#pragma unroll
  for (int sweep = 0; sweep < 4; ++sweep) {
    ROT(A00, A11, A01, A02, A12, Q00, Q01, Q10, Q11, Q20, Q21);
    ROT(A00, A22, A02, A01, A12, Q00, Q02, Q10, Q12, Q20, Q22);
    ROT(A11, A22, A12, A01, A02, Q01, Q02, Q11, Q12, Q21, Q22);
  }
#undef ROT

  float w0 = A00, w1 = A11, w2 = A22;
#define CSWAP(wa, wb, qa0, qb0, qa1, qb1, qa2, qb2)                          \
  {                                                                          \
    bool sw = (wb) < (wa);                                                   \
    float tw = wa; wa = sw ? wb : wa; wb = sw ? tw : wb;                     \
    float t0 = qa0; qa0 = sw ? qb0 : qa0; qb0 = sw ? t0 : qb0;               \
    float t1 = qa1; qa1 = sw ? qb1 : qa1; qb1 = sw ? t1 : qb1;               \
    float t2 = qa2; qa2 = sw ? qb2 : qa2; qb2 = sw ? t2 : qb2;               \
  }
  CSWAP(w0, w1, Q00, Q01, Q10, Q11, Q20, Q21);
  CSWAP(w1, w2, Q01, Q02, Q11, Q12, Q21, Q22);
  CSWAP(w0, w1, Q00, Q01, Q10, Q11, Q20, Q21);
#undef CSWAP

  Q[0][0] = Q00; Q[0][1] = Q01; Q[0][2] = Q02;
  Q[1][0] = Q10; Q[1][1] = Q11; Q[1][2] = Q12;
  Q[2][0] = Q20; Q[2][1] = Q21; Q[2][2] = Q22;
}

// ---------------------------------------------------------------------------
// Kernel 2 (fused): moments + eigen + sign + output. 16 lanes/graph,
// 16 graphs per 256-thread block.
// Phase A (R8's proven staging): unroll-5 clamped scalar loads (15 loads in
//   flight, one waitcnt round, covers 80 atoms; rare epilogue loop), 16-lane
//   butterfly reduction of 9 raw moments. Lanes sub<4 stash their raw k=0
//   atom (= atoms s..s+3); lane 0 stashes moments + {s,cnt} in LDS.
// Phase B: threads 0..15 run Jacobi + sign (first-4 atoms from LDS; global
//   fallback ~never taken) + output write, one graph each.
// ---------------------------------------------------------------------------
__global__ __launch_bounds__(256) void fused_kernel(
    const float* __restrict__ pos, const int* __restrict__ wsi,
    float* __restrict__ out, int G) {
  __shared__ float lmom[16][9];   // cx,cy,cz,ixx,iyy,izz,ixy,ixz,iyz
  __shared__ float latm[16][12];  // first 4 atoms, raw
  __shared__ int lsc[16][2];      // s, cnt

  int tid = (int)threadIdx.x;
  int lg = tid >> 4;   // local graph index within block
  int sub = tid & 15;  // lane within subgroup
  int gid = (int)blockIdx.x * 16 + lg;
  bool gv = gid < G;

  int s = 0, e = 0;
  if (gv) {
    s = wsi[gid];
    e = wsi[gid + 1];
  }
  int cnt = e - s;

  float sx = 0.f, sy = 0.f, sz = 0.f;
  float sxx = 0.f, syy = 0.f, szz = 0.f, sxy = 0.f, sxz = 0.f, syz = 0.f;
  float r0x = 0.f, r0y = 0.f, r0z = 0.f;  // raw k=0 atom (atom s+sub)

#pragma unroll
  for (int k = 0; k < 5; ++k) {
    int i = s + sub + 16 * k;
    bool in = i < e;
    int ii = in ? i : 0;                  // always-valid address
    float rx = pos[3 * ii + 0];
    float ry = pos[3 * ii + 1];
    float rz = pos[3 * ii + 2];
    if (k == 0) { r0x = rx; r0y = ry; r0z = rz; }
    float m = in ? 1.0f : 0.0f;
    float x = rx * m, y = ry * m, z = rz * m;
    sx += x; sy += y; sz += z;
    sxx = fmaf(x, x, sxx); syy = fmaf(y, y, syy); szz = fmaf(z, z, szz);
    sxy = fmaf(x, y, sxy); sxz = fmaf(x, z, sxz); syz = fmaf(y, z, syz);
  }
  for (int i = s + 80 + sub; i < e; i += 16) {  // rare: graphs > 80 atoms
    float x = pos[3 * i + 0];
    float y = pos[3 * i + 1];
    float z = pos[3 * i + 2];
    sx += x; sy += y; sz += z;
    sxx = fmaf(x, x, sxx); syy = fmaf(y, y, syy); szz = fmaf(z, z, szz);
    sxy = fmaf(x, y, sxy); sxz = fmaf(x, z, sxz); syz = fmaf(y, z, syz);
  }

#define RED16(v)                                                             \
  v += __shfl_xor(v, 1); v += __shfl_xor(v, 2);                              \
  v += __shfl_xor(v, 4); v += __shfl_xor(v, 8);
  RED16(sx) RED16(sy) RED16(sz)
  RED16(sxx) RED16(syy) RED16(szz)
  RED16(sxy) RED16(sxz) RED16(syz)
#undef RED16

  // stash first-4 raw atoms (lanes 0..3 staged atoms s..s+3 at k=0)
  if (sub < 4 && gv) {
    latm[lg][3 * sub + 0] = r0x;
    latm[lg][3 * sub + 1] = r0y;
    latm[lg][3 * sub + 2] = r0z;
  }
  if (sub == 0 && gv) {
    float fn = (float)(cnt > 0 ? cnt : 1);
    float inv = 1.0f / fn;
    float mx = sx * inv, my = sy * inv, mz = sz * inv;
    float Sxx = fmaf(-fn * mx, mx, sxx);
    float Syy = fmaf(-fn * my, my, syy);
    float Szz = fmaf(-fn * mz, mz, szz);
    float Sxy = fmaf(-fn * mx, my, sxy);
    float Sxz = fmaf(-fn * mx, mz, sxz);
    float Syz = fmaf(-fn * my, mz, syz);
    lmom[lg][0] = mx; lmom[lg][1] = my; lmom[lg][2] = mz;
    lmom[lg][3] = Syy + Szz;   // ixx
    lmom[lg][4] = Sxx + Szz;   // iyy
    lmom[lg][5] = Sxx + Syy;   // izz
    lmom[lg][6] = -Sxy;        // ixy
    lmom[lg][7] = -Sxz;        // ixz
    lmom[lg][8] = -Syz;        // iyz
    lsc[lg][0] = s; lsc[lg][1] = cnt;
  }
  __syncthreads();

  // ---- phase B: one thread per graph -------------------------------------
  if (tid < 16) {
    int g = (int)blockIdx.x * 16 + tid;
    if (g < G) {
      float cx = lmom[tid][0], cy = lmom[tid][1], cz = lmom[tid][2];
      float Q[3][3];
      jacobi3_f32(lmom[tid][3], lmom[tid][4], lmom[tid][5], lmom[tid][6],
                  lmom[tid][7], lmom[tid][8], Q);

      float q00 = Q[0][0], q10 = Q[1][0], q20 = Q[2][0];
      float q01 = Q[0][1], q11 = Q[1][1], q21 = Q[2][1];

      int s2 = lsc[tid][0];
      int cnt2 = lsc[tid][1];

      bool found0 = false, found1 = false;
      float v0s = 0.f, v1s = 0.f;
#define CHECK(J)                                                             \
  if ((J) < cnt2) {                                                          \
    float x = latm[tid][3 * (J) + 0] - cx;                                   \
    float y = latm[tid][3 * (J) + 1] - cy;                                   \
    float z = latm[tid][3 * (J) + 2] - cz;                                   \
    float p0 = x * q00 + y * q10 + z * q20;                                  \
    float p1 = x * q01 + y * q11 + z * q21;                                  \
    if (!found0 && fabsf(p0) > CANON_EPS) { v0s = p0; found0 = true; }       \
    if (!found1 && fabsf(p1) > CANON_EPS) { v1s = p1; found1 = true; }       \
  }
      CHECK(0) CHECK(1) CHECK(2) CHECK(3)
#undef CHECK
      // ~never taken: sign not decided within the first 4 atoms
      for (int i = s2 + 4; i < s2 + cnt2 && !(found0 && found1); ++i) {
        float x = pos[3 * i + 0] - cx;
        float y = pos[3 * i + 1] - cy;
        float z = pos[3 * i + 2] - cz;
        float p0 = x * q00 + y * q10 + z * q20;
        float p1 = x * q01 + y * q11 + z * q21;
        if (!found0 && fabsf(p0) > CANON_EPS) { v0s = p0; found0 = true; }
        if (!found1 && fabsf(p1) > CANON_EPS) { v1s = p1; found1 = true; }
      }
      float s0 = (found0 && v0s < 0.f) ? -1.f : 1.f;
      float s1 = (found1 && v1s < 0.f) ? -1.f : 1.f;

      float q0x = q00 * s0, q0y = q10 * s0, q0z = q20 * s0;
      float q1x = q01 * s1, q1y = q11 * s1, q1z = q21 * s1;
      float q2x = q0y * q1z - q0z * q1y;
      float q2y = q0z * q1x - q0x * q1z;
      float q2z = q0x * q1y - q0y * q1x;
      float* o = out + (size_t)g * 9;
      o[0] = q0x; o[1] = q1x; o[2] = q2x;
      o[3] = q0y; o[4] = q1y; o[5] = q2y;
      o[6] = q0z; o[7] = q1z; o[8] = q2z;
    }
  }
}

extern "C" void kernel_launch(void* const* d_in, const int* in_sizes, int n_in,
                              void* d_out, int out_size, void* d_ws, size_t ws_size,
                              hipStream_t stream) {
  const float* pos = (const float*)d_in[0];
  const int* batch = (const int*)d_in[1];
  float* out = (float*)d_out;

  int n = in_sizes[0] / 3;  // N atoms
  int G = out_size / 9;     // graphs

  int* wsi = (int*)d_ws;  // (G+1) ints: graph start offsets

  int t1 = (n + 3) / 4;
  build_starts_kernel<<<(t1 + 255) / 256, 256, 0, stream>>>(batch, wsi, n, G);

  // 16 graphs per 256-thread block
  fused_kernel<<<(G + 15) / 16, 256, 0, stream>>>(pos, wsi, out, G);
}

// Round 11
// 21.088 us; speedup vs baseline: 1.1013x; 1.0460x over previous
//
#include <hip/hip_runtime.h>
#include <math.h>

#define CANON_EPS 1e-4f

// ---------------------------------------------------------------------------
// Branch-free 3x3 symmetric Jacobi eigensolver in f32, 4 cyclic sweeps.
// Columns of Q = eigenvectors; eigenvalues sorted ascending (matches eigh).
// ---------------------------------------------------------------------------
__device__ __forceinline__ void jacobi3_f32(float a00, float a11, float a22,
                                            float a01, float a02, float a12,
                                            float Q[3][3]) {
  float A00 = a00, A11 = a11, A22 = a22;
  float A01 = a01, A02 = a02, A12 = a12;
  float Q00 = 1.f, Q01 = 0.f, Q02 = 0.f;
  float Q10 = 0.f, Q11 = 1.f, Q12 = 0.f;
  float Q20 = 0.f, Q21 = 0.f, Q22 = 1.f;

#define ROT(App, Aqq, Apq, Akp, Akq, Qrp0, Qrq0, Qrp1, Qrq1, Qrp2, Qrq2)     \
  {                                                                          \
    float apq = Apq;                                                         \
    float theta = (Aqq - App) / (2.0f * apq);                                \
    float t = copysignf(1.0f, theta) /                                       \
              (fabsf(theta) + sqrtf(1.0f + theta * theta));                  \
    t = (apq == 0.0f) ? 0.0f : t; /* kills 0/0 NaN path */                   \
    float c = 1.0f / sqrtf(1.0f + t * t);                                    \
    float s = t * c;                                                         \
    App = App - t * apq;                                                     \
    Aqq = Aqq + t * apq;                                                     \
    Apq = 0.0f;                                                              \
    float akp = Akp, akq = Akq;                                              \
    Akp = c * akp - s * akq;                                                 \
    Akq = s * akp + c * akq;                                                 \
    float r0p = Qrp0, r0q = Qrq0;                                            \
    Qrp0 = c * r0p - s * r0q;                                                \
    Qrq0 = s * r0p + c * r0q;                                                \
    float r1p = Qrp1, r1q = Qrq1;                                            \
    Qrp1 = c * r1p - s * r1q;                                                \
    Qrq1 = s * r1p + c * r1q;                                                \
    float r2p = Qrp2, r2q = Qrq2;                                            \
    Qrp2 = c * r2p - s * r2q;                                                \
    Qrq2 = s * r2p + c * r2q;                                                \
  }

#pragma unroll
  for (int sweep = 0; sweep < 4; ++sweep) {
    ROT(A00, A11, A01, A02, A12, Q00, Q01, Q10, Q11, Q20, Q21);
    ROT(A00, A22, A02, A01, A12, Q00, Q02, Q10, Q12, Q20, Q22);
    ROT(A11, A22, A12, A01, A02, Q01, Q02, Q11, Q12, Q21, Q22);
  }
#undef ROT

  float w0 = A00, w1 = A11, w2 = A22;
#define CSWAP(wa, wb, qa0, qb0, qa1, qb1, qa2, qb2)                          \
  {                                                                          \
    bool sw = (wb) < (wa);                                                   \
    float tw = wa; wa = sw ? wb : wa; wb = sw ? tw : wb;                     \
    float t0 = qa0; qa0 = sw ? qb0 : qa0; qb0 = sw ? t0 : qb0;               \
    float t1 = qa1; qa1 = sw ? qb1 : qa1; qb1 = sw ? t1 : qb1;               \
    float t2 = qa2; qa2 = sw ? qb2 : qa2; qb2 = sw ? t2 : qb2;               \
  }
  CSWAP(w0, w1, Q00, Q01, Q10, Q11, Q20, Q21);
  CSWAP(w1, w2, Q01, Q02, Q11, Q12, Q21, Q22);
  CSWAP(w0, w1, Q00, Q01, Q10, Q11, Q20, Q21);
#undef CSWAP

  Q[0][0] = Q00; Q[0][1] = Q01; Q[0][2] = Q02;
  Q[1][0] = Q10; Q[1][1] = Q11; Q[1][2] = Q12;
  Q[2][0] = Q20; Q[2][1] = Q21; Q[2][2] = Q22;
}

// ---------------------------------------------------------------------------
// Single fused kernel: bounds (cooperative 8-ary search) + moments + eigen +
// sign + output. 16 lanes per graph, 16 graphs per 256-thread block.
//
// Search: within each 16-lane subgroup, lanes 0..7 handle target gid, lanes
// 8..15 handle gid+1 (lb = first index with batch >= target). Each round
// probes 7 split points of the current 8^k window; __ballot + popcount
// collapse the window 8x. log8(2^21) = 7 rounds + 1 fix-up round. All lanes
// redundantly maintain both bounds -> no broadcast needed.
// ---------------------------------------------------------------------------
__global__ __launch_bounds__(256) void canon_all_kernel(
    const float* __restrict__ pos, const int* __restrict__ batch,
    float* __restrict__ out, int n, int G) {
  __shared__ float lmom[16][9];   // cx,cy,cz,ixx,iyy,izz,ixy,ixz,iyz
  __shared__ float latm[16][12];  // first 4 atoms, raw
  __shared__ int lsc[16][2];      // s, cnt

  int tid = (int)threadIdx.x;
  int lg = tid >> 4;    // local graph index within block
  int sub = tid & 15;   // lane within subgroup
  int lane = tid & 63;  // lane within wave
  int gid = (int)blockIdx.x * 16 + lg;
  bool gv = gid < G;

  // ---- cooperative 8-ary lower-bound search ------------------------------
  int t0 = gv ? gid : (G - 1);
  int half = (lane >> 3) & 1;  // 0: target t0, 1: target t0+1
  int tgt = t0 + half;
  int j = lane & 7;            // probe slot within half (j=0: trivial true)
  int base = lane & 0x30;      // subgroup's bit base in the 64-bit ballot

  int r = 1;
  while (r < n) r <<= 3;       // power of 8 >= n (wave-uniform SALU loop)
  int lo0 = 0, lo1 = 0;
  while (r > 1) {
    int step = r >> 3;
    int myLo = half ? lo1 : lo0;
    int m = myLo + j * step;   // probe: is lb >= m ? <=> batch[m-1] < tgt
    int mm = m - 1;
    mm = mm < 0 ? 0 : (mm > n - 1 ? n - 1 : mm);
    bool c = (j == 0) || ((m <= n) && (batch[mm] < tgt));
    unsigned long long b = __ballot(c);
    unsigned c0 = (unsigned)((b >> base) & 0xFEull);         // bits 1..7
    unsigned c1 = (unsigned)((b >> (base + 8)) & 0xFEull);   // bits 1..7
    lo0 += __popc(c0) * step;
    lo1 += __popc(c1) * step;
    r = step;
  }
  {  // final fix-up: lb = lo + (batch[lo] < tgt)
    int i0 = lo0 < n - 1 ? lo0 : n - 1;
    int i1 = lo1 < n - 1 ? lo1 : n - 1;
    lo0 += ((lo0 < n) && (batch[i0] < t0)) ? 1 : 0;
    lo1 += ((lo1 < n) && (batch[i1] < t0 + 1)) ? 1 : 0;
  }
  int s = lo0, e = lo1;
  int cnt = e - s;

  // ---- moments: unroll-5 clamped scalar loads, one waitcnt round ---------
  float sx = 0.f, sy = 0.f, sz = 0.f;
  float sxx = 0.f, syy = 0.f, szz = 0.f, sxy = 0.f, sxz = 0.f, syz = 0.f;
  float r0x = 0.f, r0y = 0.f, r0z = 0.f;  // raw k=0 atom (atom s+sub)

#pragma unroll
  for (int k = 0; k < 5; ++k) {
    int i = s + sub + 16 * k;
    bool in = i < e;
    int ii = in ? i : 0;  // always-valid address
    float rx = pos[3 * ii + 0];
    float ry = pos[3 * ii + 1];
    float rz = pos[3 * ii + 2];
    if (k == 0) { r0x = rx; r0y = ry; r0z = rz; }
    float m = in ? 1.0f : 0.0f;
    float x = rx * m, y = ry * m, z = rz * m;
    sx += x; sy += y; sz += z;
    sxx = fmaf(x, x, sxx); syy = fmaf(y, y, syy); szz = fmaf(z, z, szz);
    sxy = fmaf(x, y, sxy); sxz = fmaf(x, z, sxz); syz = fmaf(y, z, syz);
  }
  for (int i = s + 80 + sub; i < e; i += 16) {  // rare: graphs > 80 atoms
    float x = pos[3 * i + 0];
    float y = pos[3 * i + 1];
    float z = pos[3 * i + 2];
    sx += x; sy += y; sz += z;
    sxx = fmaf(x, x, sxx); syy = fmaf(y, y, syy); szz = fmaf(z, z, szz);
    sxy = fmaf(x, y, sxy); sxz = fmaf(x, z, sxz); syz = fmaf(y, z, syz);
  }

#define RED16(v)                                                             \
  v += __shfl_xor(v, 1); v += __shfl_xor(v, 2);                              \
  v += __shfl_xor(v, 4); v += __shfl_xor(v, 8);
  RED16(sx) RED16(sy) RED16(sz)
  RED16(sxx) RED16(syy) RED16(szz)
  RED16(sxy) RED16(sxz) RED16(syz)
#undef RED16

  // stash first-4 raw atoms (lanes 0..3 staged atoms s..s+3 at k=0)
  if (sub < 4 && gv) {
    latm[lg][3 * sub + 0] = r0x;
    latm[lg][3 * sub + 1] = r0y;
    latm[lg][3 * sub + 2] = r0z;
  }
  if (sub == 0 && gv) {
    float fn = (float)(cnt > 0 ? cnt : 1);
    float inv = 1.0f / fn;
    float mx = sx * inv, my = sy * inv, mz = sz * inv;
    float Sxx = fmaf(-fn * mx, mx, sxx);
    float Syy = fmaf(-fn * my, my, syy);
    float Szz = fmaf(-fn * mz, mz, szz);
    float Sxy = fmaf(-fn * mx, my, sxy);
    float Sxz = fmaf(-fn * mx, mz, sxz);
    float Syz = fmaf(-fn * my, mz, syz);
    lmom[lg][0] = mx; lmom[lg][1] = my; lmom[lg][2] = mz;
    lmom[lg][3] = Syy + Szz;   // ixx
    lmom[lg][4] = Sxx + Szz;   // iyy
    lmom[lg][5] = Sxx + Syy;   // izz
    lmom[lg][6] = -Sxy;        // ixy
    lmom[lg][7] = -Sxz;        // ixz
    lmom[lg][8] = -Syz;        // iyz
    lsc[lg][0] = s; lsc[lg][1] = cnt;
  }
  __syncthreads();

  // ---- phase B: one thread per graph -------------------------------------
  if (tid < 16) {
    int g = (int)blockIdx.x * 16 + tid;
    if (g < G) {
      float cx = lmom[tid][0], cy = lmom[tid][1], cz = lmom[tid][2];
      float Q[3][3];
      jacobi3_f32(lmom[tid][3], lmom[tid][4], lmom[tid][5], lmom[tid][6],
                  lmom[tid][7], lmom[tid][8], Q);

      float q00 = Q[0][0], q10 = Q[1][0], q20 = Q[2][0];
      float q01 = Q[0][1], q11 = Q[1][1], q21 = Q[2][1];

      int s2 = lsc[tid][0];
      int cnt2 = lsc[tid][1];

      bool found0 = false, found1 = false;
      float v0s = 0.f, v1s = 0.f;
#define CHECK(J)                                                             \
  if ((J) < cnt2) {                                                          \
    float x = latm[tid][3 * (J) + 0] - cx;                                   \
    float y = latm[tid][3 * (J) + 1] - cy;                                   \
    float z = latm[tid][3 * (J) + 2] - cz;                                   \
    float p0 = x * q00 + y * q10 + z * q20;                                  \
    float p1 = x * q01 + y * q11 + z * q21;                                  \
    if (!found0 && fabsf(p0) > CANON_EPS) { v0s = p0; found0 = true; }       \
    if (!found1 && fabsf(p1) > CANON_EPS) { v1s = p1; found1 = true; }       \
  }
      CHECK(0) CHECK(1) CHECK(2) CHECK(3)
#undef CHECK
      // ~never taken: sign not decided within the first 4 atoms
      for (int i = s2 + 4; i < s2 + cnt2 && !(found0 && found1); ++i) {
        float x = pos[3 * i + 0] - cx;
        float y = pos[3 * i + 1] - cy;
        float z = pos[3 * i + 2] - cz;
        float p0 = x * q00 + y * q10 + z * q20;
        float p1 = x * q01 + y * q11 + z * q21;
        if (!found0 && fabsf(p0) > CANON_EPS) { v0s = p0; found0 = true; }
        if (!found1 && fabsf(p1) > CANON_EPS) { v1s = p1; found1 = true; }
      }
      float s0 = (found0 && v0s < 0.f) ? -1.f : 1.f;
      float s1 = (found1 && v1s < 0.f) ? -1.f : 1.f;

      float q0x = q00 * s0, q0y = q10 * s0, q0z = q20 * s0;
      float q1x = q01 * s1, q1y = q11 * s1, q1z = q21 * s1;
      float q2x = q0y * q1z - q0z * q1y;
      float q2y = q0z * q1x - q0x * q1z;
      float q2z = q0x * q1y - q0y * q1x;
      float* o = out + (size_t)g * 9;
      o[0] = q0x; o[1] = q1x; o[2] = q2x;
      o[3] = q0y; o[4] = q1y; o[5] = q2y;
      o[6] = q0z; o[7] = q1z; o[8] = q2z;
    }
  }
}

extern "C" void kernel_launch(void* const* d_in, const int* in_sizes, int n_in,
                              void* d_out, int out_size, void* d_ws, size_t ws_size,
                              hipStream_t stream) {
  const float* pos = (const float*)d_in[0];
  const int* batch = (const int*)d_in[1];
  float* out = (float*)d_out;

  int n = in_sizes[0] / 3;  // N atoms
  int G = out_size / 9;     // graphs

  // one kernel: 16 graphs per 256-thread block
  canon_all_kernel<<<(G + 15) / 16, 256, 0, stream>>>(pos, batch, out, n, G);
}